// Round 9
// baseline (92.969 us; speedup 1.0000x reference)
//
#include <hip/hip_runtime.h>

#define N 4096

// pad-17 float layout: logical index p -> slot p + (p>>4). 2-way max bank
// aliasing for all four patterns (T1w t*17+i, T1r/T2w b1*272+j*17+c1,
// T2r j*272+t+(t>>4)); additive -> ds immediate offsets.
__global__ __launch_bounds__(256, 8) void butterfly9_kernel(
    const float* __restrict__ x,
    const float* __restrict__ w0, const float* __restrict__ w1, const float* __restrict__ w2,
    const float* __restrict__ l0, const float* __restrict__ l1, const float* __restrict__ l2,
    float* __restrict__ out)
{
    __shared__ float lds[N + (N >> 4)];   // 17408 B -> 9 blocks/CU (cap 8 by waves)
    const int t = threadIdx.x;
    const int b1 = t >> 4, c1 = t & 15;
    const float* __restrict__ xr = x + (size_t)blockIdx.x * N;
    float* __restrict__ orow = out + (size_t)blockIdx.x * N;

    // ---- load 16 contiguous elements (4 x dwordx4) ----
    float v[16];
    {
        const float4* xq = (const float4*)(xr + t * 16);
        #pragma unroll
        for (int q = 0; q < 4; ++q) {
            float4 f = xq[q];
            v[q*4+0]=f.x; v[q*4+1]=f.y; v[q*4+2]=f.z; v[q*4+3]=f.w;
        }
    }

    // ---- level 2 (thread-local 16x16 matvec, residual = x) ----
    float xw[16];
    #pragma unroll
    for (int j = 0; j < 16; ++j) xw[j] = w2[j] * v[j];        // uniform -> SGPR
    #pragma unroll
    for (int i = 0; i < 16; ++i) {
        float acc = v[i];
        #pragma unroll
        for (int j = 0; j < 16; ++j) acc = fmaf(l2[i*16+j], xw[j], acc);
        lds[t*17 + i] = acc;                                   // wave-private region
    }

    float w1c[16];
    #pragma unroll
    for (int j = 0; j < 16; ++j) w1c[j] = w1[j*16 + c1];

    // ---- level 1 (intra-wave exchange, no barrier, no residual) ----
    float y1[16];
    #pragma unroll
    for (int j = 0; j < 16; ++j)
        y1[j] = w1c[j] * lds[b1*272 + j*17 + c1];              // same-wave writers
    float r1[16];
    #pragma unroll
    for (int i = 0; i < 16; ++i) {
        float acc = 0.f;
        #pragma unroll
        for (int j = 0; j < 16; ++j) acc = fmaf(l1[i*16+j], y1[j], acc);
        r1[i] = acc;
    }
    #pragma unroll
    for (int i = 0; i < 16; ++i)
        lds[b1*272 + i*17 + c1] = r1[i];                       // WAR on own wave's slots

    float w0c[16];
    #pragma unroll
    for (int j = 0; j < 16; ++j) w0c[j] = w0[j*256 + t];

    __syncthreads();                      // single cross-wave handoff

    // ---- level 0 (stride-256 mix, residual = original x), NT full-line stores ----
    const int tb = t + (t >> 4);
    float y0[16];
    #pragma unroll
    for (int j = 0; j < 16; ++j)
        y0[j] = w0c[j] * lds[j*272 + tb];
    #pragma unroll
    for (int i = 0; i < 16; ++i) {
        float acc = xr[i*256 + t];        // residual re-read: L2/L3-hot
        #pragma unroll
        for (int j = 0; j < 16; ++j) acc = fmaf(l0[i*16+j], y0[j], acc);
        __builtin_nontemporal_store(acc, &orow[i*256 + t]);   // 256B/inst: full lines
    }
}

extern "C" void kernel_launch(void* const* d_in, const int* in_sizes, int n_in,
                              void* d_out, int out_size, void* d_ws, size_t ws_size,
                              hipStream_t stream) {
    const float* x  = (const float*)d_in[0];
    const float* w0 = (const float*)d_in[1];
    const float* w1 = (const float*)d_in[2];
    const float* w2 = (const float*)d_in[3];
    const float* l0 = (const float*)d_in[4];
    const float* l1 = (const float*)d_in[5];
    const float* l2 = (const float*)d_in[6];
    float* out = (float*)d_out;
    const int rows = in_sizes[0] / N;
    butterfly9_kernel<<<rows, 256, 0, stream>>>(x, w0, w1, w2, l0, l1, l2, out);
}